// Round 1
// baseline (1681.573 us; speedup 1.0000x reference)
//
#include <hip/hip_runtime.h>

static constexpr int NHID = 32;

// ---------------------------------------------------------------------------
// Edge kernel: one thread per edge.
//   h_k   = relu(edge_attr @ w1 + b1)[k]        (recomputed per k, stays in regs)
//   msg_o = sum_i x[src]_i * (sum_k h_k w2[k,i,o] + b2[i,o])
//   atomicAdd into agg[dst]
// w1/b1/w2/b2 addresses are wave-uniform -> scalar-cache broadcast loads.
// ---------------------------------------------------------------------------
template<int IN_C, int OUT_C, bool RELU_IN, int XSTRIDE, int XOFF>
__global__ __launch_bounds__(256) void nnconv_edge(
    const float* __restrict__ xfeat,
    const int*   __restrict__ srcv,
    const int*   __restrict__ dstv,
    const float* __restrict__ ea,
    const float* __restrict__ w1,
    const float* __restrict__ b1,
    const float* __restrict__ w2,
    const float* __restrict__ b2,
    float* __restrict__ agg,
    int E)
{
    int e = blockIdx.x * 256 + threadIdx.x;
    if (e >= E) return;

    float4 a = *reinterpret_cast<const float4*>(ea + 4ll * e);
    int s = srcv[e];
    int d = dstv[e];

    const float* xp = xfeat + (long long)s * XSTRIDE + XOFF;
    float x[IN_C];
    if constexpr ((IN_C % 4 == 0) && (XSTRIDE % 4 == 0) && (XOFF % 4 == 0)) {
        #pragma unroll
        for (int i4 = 0; i4 < IN_C / 4; ++i4) {
            float4 v = reinterpret_cast<const float4*>(xp)[i4];
            x[4*i4+0] = v.x; x[4*i4+1] = v.y; x[4*i4+2] = v.z; x[4*i4+3] = v.w;
        }
    } else {
        #pragma unroll
        for (int i = 0; i < IN_C; ++i) x[i] = xp[i];
    }
    if constexpr (RELU_IN) {
        #pragma unroll
        for (int i = 0; i < IN_C; ++i) x[i] = fmaxf(x[i], 0.f);
    }

    float msg[OUT_C];
    #pragma unroll
    for (int o = 0; o < OUT_C; ++o) msg[o] = 0.f;

    // b2 contribution: msg_o += sum_i x_i * b2[i,o]
    #pragma unroll
    for (int i = 0; i < IN_C; ++i) {
        #pragma unroll
        for (int o = 0; o < OUT_C; ++o)
            msg[o] = fmaf(x[i], b2[i * OUT_C + o], msg[o]);
    }

    // main contraction; h_k recomputed each iteration (5 VALU per 1024 FMAs)
    #pragma unroll 1
    for (int k = 0; k < NHID; ++k) {
        float hk = fmaf(a.x, w1[0 * NHID + k], b1[k]);
        hk = fmaf(a.y, w1[1 * NHID + k], hk);
        hk = fmaf(a.z, w1[2 * NHID + k], hk);
        hk = fmaf(a.w, w1[3 * NHID + k], hk);
        hk = fmaxf(hk, 0.f);
        const float* w2k = w2 + (long long)k * (IN_C * OUT_C);
        #pragma unroll
        for (int i = 0; i < IN_C; ++i) {
            float t = hk * x[i];
            #pragma unroll
            for (int o = 0; o < OUT_C; ++o)
                msg[o] = fmaf(t, w2k[i * OUT_C + o], msg[o]);
        }
    }

    float* ap = agg + (long long)d * OUT_C;
    #pragma unroll
    for (int o = 0; o < OUT_C; ++o)
        unsafeAtomicAdd(ap + o, msg[o]);   // hw global_atomic_add_f32
}

// ---------------------------------------------------------------------------
// Node kernel: out[n] = bias + x[n] @ root. Runs BEFORE the edge kernel of the
// same layer, so the agg buffer never needs zeroing (ws is 0xAA-poisoned).
// ---------------------------------------------------------------------------
template<int IN_C, int OUT_C, bool RELU_IN, int XSTRIDE, int XOFF>
__global__ __launch_bounds__(256) void nnconv_node(
    const float* __restrict__ xfeat,
    const float* __restrict__ root,
    const float* __restrict__ bias,
    float* __restrict__ outbuf,
    int N)
{
    int n = blockIdx.x * 256 + threadIdx.x;
    if (n >= N) return;

    const float* xp = xfeat + (long long)n * XSTRIDE + XOFF;
    float x[IN_C];
    if constexpr ((IN_C % 4 == 0) && (XSTRIDE % 4 == 0) && (XOFF % 4 == 0)) {
        #pragma unroll
        for (int i4 = 0; i4 < IN_C / 4; ++i4) {
            float4 v = reinterpret_cast<const float4*>(xp)[i4];
            x[4*i4+0] = v.x; x[4*i4+1] = v.y; x[4*i4+2] = v.z; x[4*i4+3] = v.w;
        }
    } else {
        #pragma unroll
        for (int i = 0; i < IN_C; ++i) x[i] = xp[i];
    }
    if constexpr (RELU_IN) {
        #pragma unroll
        for (int i = 0; i < IN_C; ++i) x[i] = fmaxf(x[i], 0.f);
    }

    float acc[OUT_C];
    #pragma unroll
    for (int o = 0; o < OUT_C; ++o) acc[o] = bias[o];
    #pragma unroll
    for (int i = 0; i < IN_C; ++i) {
        #pragma unroll
        for (int o = 0; o < OUT_C; ++o)
            acc[o] = fmaf(x[i], root[i * OUT_C + o], acc[o]);
    }

    float* op = outbuf + (long long)n * OUT_C;
    #pragma unroll
    for (int o = 0; o < OUT_C; ++o) op[o] = acc[o];
}

// ---------------------------------------------------------------------------
extern "C" void kernel_launch(void* const* d_in, const int* in_sizes, int n_in,
                              void* d_out, int out_size, void* d_ws, size_t ws_size,
                              hipStream_t stream)
{
    const float* x  = (const float*)d_in[0];
    const int*   ei = (const int*)d_in[1];     // [2, E] int32 (harness-normalized)
    const float* ea = (const float*)d_in[2];

    const int E = in_sizes[2] / 4;             // edge_attr is (E, 4)
    const int N = in_sizes[0] / 10;            // x is (N, 10)
    const int* src = ei;
    const int* dst = ei + E;

    // per-layer params: w1, b1, w2, b2, root, bias
    const float* p[4][6];
    for (int L = 0; L < 4; ++L)
        for (int j = 0; j < 6; ++j)
            p[L][j] = (const float*)d_in[3 + 6 * L + j];

    float* A = (float*)d_ws;                   // N x 32
    float* B = A + (size_t)N * NHID;           // N x 32
    float* out = (float*)d_out;                // N x 2

    const int eb = (E + 255) / 256;
    const int nb = (N + 255) / 256;

    // layer 0: x[:,4:10] -> A
    nnconv_node<6, 32, false, 10, 4><<<nb, 256, 0, stream>>>(x, p[0][4], p[0][5], A, N);
    nnconv_edge<6, 32, false, 10, 4><<<eb, 256, 0, stream>>>(x, src, dst, ea,
        p[0][0], p[0][1], p[0][2], p[0][3], A, E);

    // layer 1: relu(A) -> B
    nnconv_node<32, 32, true, 32, 0><<<nb, 256, 0, stream>>>(A, p[1][4], p[1][5], B, N);
    nnconv_edge<32, 32, true, 32, 0><<<eb, 256, 0, stream>>>(A, src, dst, ea,
        p[1][0], p[1][1], p[1][2], p[1][3], B, E);

    // layer 2: relu(B) -> A
    nnconv_node<32, 32, true, 32, 0><<<nb, 256, 0, stream>>>(B, p[2][4], p[2][5], A, N);
    nnconv_edge<32, 32, true, 32, 0><<<eb, 256, 0, stream>>>(B, src, dst, ea,
        p[2][0], p[2][1], p[2][2], p[2][3], A, E);

    // layer 3: relu(A) -> out   (no final activation)
    nnconv_node<32, 2, true, 32, 0><<<nb, 256, 0, stream>>>(A, p[3][4], p[3][5], out, N);
    nnconv_edge<32, 2, true, 32, 0><<<eb, 256, 0, stream>>>(A, src, dst, ea,
        p[3][0], p[3][1], p[3][2], p[3][3], out, E);
}

// Round 2
// 193.898 us; speedup vs baseline: 8.6725x; 8.6725x over previous
//
#include <hip/hip_runtime.h>
#include <hip/hip_bf16.h>

static constexpr int NHID = 32;

typedef __attribute__((ext_vector_type(8)))  short short8v;  // 8 bf16
typedef __attribute__((ext_vector_type(16))) float f32x16;

union ABfrag { short8v v; short s[8]; };

static __device__ __forceinline__ short f2bf(float f) {
    __hip_bfloat16 h = __float2bfloat16(f);   // RNE
    return __builtin_bit_cast(short, h);
}

// ---------------------------------------------------------------------------
// Pre-swizzle w2 (+ b2 tail steps) into the mfma_f32_32x32x16_bf16 B-fragment
// layout.  kappa = k*INP + i (k-major, INP = padded IN_C).  Element (t,l,j):
//   kappa = 16*t + 8*(l>>5) + j ;  o = l&31
//   t <  S_MAIN : B = w2[k, i*OUT_C + o]          (k=kappa/INP, i=kappa%INP)
//   t >= S_MAIN : B = b2[i*OUT_C + o],  i = 16*(t-S_MAIN) + 8*(l>>5) + j
// Out-of-range (i>=IN_C or o>=OUT_C) -> 0.  The edge kernel builds A with the
// SAME (t,g,j)->kappa map, so any internal HW k-permutation cancels in the sum.
// ---------------------------------------------------------------------------
template<int INP, int IN_C, int OUT_C>
__global__ __launch_bounds__(256) void build_bswz(
    const float* __restrict__ w2, const float* __restrict__ b2,
    short* __restrict__ out)
{
    constexpr int S_MAIN = 2 * INP;            // NHID*INP/16
    constexpr int S_B2   = (INP + 15) / 16;
    constexpr int S_TOT  = S_MAIN + S_B2;
    int tid = blockIdx.x * 256 + threadIdx.x;
    if (tid >= S_TOT * 512) return;
    int j = tid & 7, l = (tid >> 3) & 63, t = tid >> 9;
    int g = l >> 5, o = l & 31;
    float v = 0.f;
    if (t < S_MAIN) {
        int kap = 16 * t + 8 * g + j;
        int k = kap / INP, i = kap % INP;
        if (i < IN_C && o < OUT_C)
            v = w2[(size_t)k * (IN_C * OUT_C) + i * OUT_C + o];
    } else {
        int i = 16 * (t - S_MAIN) + 8 * g + j;
        if (i < IN_C && o < OUT_C)
            v = b2[i * OUT_C + o];
    }
    out[tid] = f2bf(v);
}

// ---------------------------------------------------------------------------
// Edge kernel, MFMA path.  One wave = 32 edges (M-tile), N = 32 (o, padded),
// K = NHID*INP + INP (b2 tail).  A generated in-register per kappa-step:
//   INP==32: k = t>>1 (step-uniform)  -> a_j = h[t>>1] * xr[(t&1)*8 + j]
//   INP==8 : k = 2t+g (lane's g)      -> a_j = h[2t+g] * xr[j]
// C layout (m74/m101 verified): col = lane&31 = o, row = (r&3)+8*(r>>2)+4*g.
// Epilogue: 32 lanes of a row hit agg[dst*OUT_C + 0..31] = 2 contiguous lines.
// ---------------------------------------------------------------------------
template<int INP, int IN_C, int OUT_C, bool RELU_IN, int XSTRIDE, int XOFF>
__global__ __launch_bounds__(256) void nnconv_edge_mfma(
    const float* __restrict__ xfeat,
    const int*   __restrict__ srcv,
    const int*   __restrict__ dstv,
    const float* __restrict__ ea,
    const float* __restrict__ w1,     // (4, 32) row-major
    const float* __restrict__ b1,     // (32)
    const short* __restrict__ bswz,   // pre-swizzled B fragments
    float* __restrict__ agg,          // row stride OUT_C
    int E)
{
    constexpr int S_MAIN = 2 * INP;
    constexpr int S_B2   = (INP + 15) / 16;
    constexpr int S_TOT  = S_MAIN + S_B2;

    const int lane = threadIdx.x & 63;
    const int wid  = (blockIdx.x * 256 + threadIdx.x) >> 6;
    const int e0   = wid * 32;
    if (e0 >= E) return;
    const int g = lane >> 5, o = lane & 31;

    const int er = e0 + (lane & 31);          // this lane's A-row edge
    const int ec = er < E ? er : (E - 1);
    const int s  = srcv[ec];
    const float4 av = *reinterpret_cast<const float4*>(ea + 4ll * ec);

    // h[k] = relu(ea . w1[:,k] + b1[k]) — w1/b1 wave-uniform -> scalar loads
    float h[NHID];
    #pragma unroll
    for (int k = 0; k < NHID; ++k) {
        float hk = fmaf(av.x, w1[k], b1[k]);
        hk = fmaf(av.y, w1[NHID + k], hk);
        hk = fmaf(av.z, w1[2 * NHID + k], hk);
        hk = fmaf(av.w, w1[3 * NHID + k], hk);
        h[k] = fmaxf(hk, 0.f);
    }

    // per-lane x slice (f32, static-indexed)
    constexpr int NXR = (INP == 32) ? 16 : 8;
    float xr[NXR];
    const float* xp = xfeat + (size_t)s * XSTRIDE + XOFF;
    if constexpr (INP == 32) {
        float4 v0 = *reinterpret_cast<const float4*>(xp + 8 * g);
        float4 v1 = *reinterpret_cast<const float4*>(xp + 8 * g + 4);
        float4 v2 = *reinterpret_cast<const float4*>(xp + 16 + 8 * g);
        float4 v3 = *reinterpret_cast<const float4*>(xp + 16 + 8 * g + 4);
        xr[0]=v0.x; xr[1]=v0.y; xr[2]=v0.z; xr[3]=v0.w;
        xr[4]=v1.x; xr[5]=v1.y; xr[6]=v1.z; xr[7]=v1.w;
        xr[8]=v2.x; xr[9]=v2.y; xr[10]=v2.z; xr[11]=v2.w;
        xr[12]=v3.x; xr[13]=v3.y; xr[14]=v3.z; xr[15]=v3.w;
    } else {
        #pragma unroll
        for (int j = 0; j < 8; ++j) xr[j] = (j < IN_C) ? xp[j] : 0.f;
    }
    if constexpr (RELU_IN) {
        #pragma unroll
        for (int j = 0; j < NXR; ++j) xr[j] = fmaxf(xr[j], 0.f);
    }

    f32x16 C;
    #pragma unroll
    for (int i = 0; i < 16; ++i) C[i] = 0.f;

    const short8v* bp = reinterpret_cast<const short8v*>(bswz);
    #pragma unroll
    for (int t = 0; t < S_TOT; ++t) {
        short8v bfrag = bp[t * 64 + lane];
        ABfrag a;
        if (t < S_MAIN) {
            if constexpr (INP == 32) {
                const float hk = h[t >> 1];
                const int  xb = (t & 1) * 8;
                #pragma unroll
                for (int j = 0; j < 8; ++j) a.s[j] = f2bf(hk * xr[xb + j]);
            } else {
                const float hk = g ? h[2 * t + 1] : h[2 * t];
                #pragma unroll
                for (int j = 0; j < 8; ++j) a.s[j] = f2bf(hk * xr[j]);
            }
        } else {  // b2 tail: h == 1
            if constexpr (INP == 32) {
                const int xb = (t - S_MAIN) * 8;
                #pragma unroll
                for (int j = 0; j < 8; ++j) a.s[j] = f2bf(xr[xb + j]);
            } else {
                #pragma unroll
                for (int j = 0; j < 8; ++j) a.s[j] = g ? (short)0 : f2bf(xr[j]);
            }
        }
        C = __builtin_amdgcn_mfma_f32_32x32x16_bf16(a.v, bfrag, C, 0, 0, 0);
    }

    // epilogue: reg r -> edge row (r&3) + 8*(r>>2) + 4*g, col o
    if (OUT_C == 32 || o < OUT_C) {
        #pragma unroll
        for (int q = 0; q < 4; ++q) {
            const int eb = e0 + 8 * q + 4 * g;
            if (eb + 3 < E) {
                const int4 dd = *reinterpret_cast<const int4*>(dstv + eb);
                unsafeAtomicAdd(agg + (size_t)dd.x * OUT_C + o, C[4 * q + 0]);
                unsafeAtomicAdd(agg + (size_t)dd.y * OUT_C + o, C[4 * q + 1]);
                unsafeAtomicAdd(agg + (size_t)dd.z * OUT_C + o, C[4 * q + 2]);
                unsafeAtomicAdd(agg + (size_t)dd.w * OUT_C + o, C[4 * q + 3]);
            } else {
                #pragma unroll
                for (int m = 0; m < 4; ++m)
                    if (eb + m < E)
                        unsafeAtomicAdd(agg + (size_t)dstv[eb + m] * OUT_C + o,
                                        C[4 * q + m]);
            }
        }
    }
}

// ---------------------------------------------------------------------------
// Node kernel (unchanged): out[n] = bias + x[n] @ root, runs before the edge
// kernel of its layer so agg needs no zeroing.
// ---------------------------------------------------------------------------
template<int IN_C, int OUT_C, bool RELU_IN, int XSTRIDE, int XOFF>
__global__ __launch_bounds__(256) void nnconv_node(
    const float* __restrict__ xfeat,
    const float* __restrict__ root,
    const float* __restrict__ bias,
    float* __restrict__ outbuf,
    int N)
{
    int n = blockIdx.x * 256 + threadIdx.x;
    if (n >= N) return;

    const float* xp = xfeat + (long long)n * XSTRIDE + XOFF;
    float x[IN_C];
    if constexpr ((IN_C % 4 == 0) && (XSTRIDE % 4 == 0) && (XOFF % 4 == 0)) {
        #pragma unroll
        for (int i4 = 0; i4 < IN_C / 4; ++i4) {
            float4 v = reinterpret_cast<const float4*>(xp)[i4];
            x[4*i4+0] = v.x; x[4*i4+1] = v.y; x[4*i4+2] = v.z; x[4*i4+3] = v.w;
        }
    } else {
        #pragma unroll
        for (int i = 0; i < IN_C; ++i) x[i] = xp[i];
    }
    if constexpr (RELU_IN) {
        #pragma unroll
        for (int i = 0; i < IN_C; ++i) x[i] = fmaxf(x[i], 0.f);
    }

    float acc[OUT_C];
    #pragma unroll
    for (int o = 0; o < OUT_C; ++o) acc[o] = bias[o];
    #pragma unroll
    for (int i = 0; i < IN_C; ++i) {
        #pragma unroll
        for (int o = 0; o < OUT_C; ++o)
            acc[o] = fmaf(x[i], root[i * OUT_C + o], acc[o]);
    }

    float* op = outbuf + (long long)n * OUT_C;
    #pragma unroll
    for (int o = 0; o < OUT_C; ++o) op[o] = acc[o];
}

// ---------------------------------------------------------------------------
extern "C" void kernel_launch(void* const* d_in, const int* in_sizes, int n_in,
                              void* d_out, int out_size, void* d_ws, size_t ws_size,
                              hipStream_t stream)
{
    const float* x  = (const float*)d_in[0];
    const int*   ei = (const int*)d_in[1];
    const float* ea = (const float*)d_in[2];

    const int E = in_sizes[2] / 4;
    const int N = in_sizes[0] / 10;
    const int* src = ei;
    const int* dst = ei + E;

    const float* p[4][6];   // w1, b1, w2, b2, root, bias
    for (int L = 0; L < 4; ++L)
        for (int j = 0; j < 6; ++j)
            p[L][j] = (const float*)d_in[3 + 6 * L + j];

    float* A    = (float*)d_ws;                      // N x 32
    float* Bbuf = A + (size_t)N * NHID;              // N x 32
    short* bswz0 = (short*)(Bbuf + (size_t)N * NHID);
    short* bswz1 = bswz0 + 17 * 512;                 // L0: (2*8+1)=17 steps
    short* bswz2 = bswz1 + 66 * 512;                 // L1: (2*32+2)=66 steps
    short* bswz3 = bswz2 + 66 * 512;                 // L2
    float* out  = (float*)d_out;                     // N x 2

    // pre-swizzle all B matrices (bf16 fragment layout)
    build_bswz<8, 6, 32>  <<<34,  256, 0, stream>>>(p[0][2], p[0][3], bswz0);
    build_bswz<32, 32, 32><<<132, 256, 0, stream>>>(p[1][2], p[1][3], bswz1);
    build_bswz<32, 32, 32><<<132, 256, 0, stream>>>(p[2][2], p[2][3], bswz2);
    build_bswz<32, 32, 2> <<<132, 256, 0, stream>>>(p[3][2], p[3][3], bswz3);

    const int nwaves  = (E + 31) / 32;
    const int eblocks = (nwaves + 3) / 4;            // 4 waves / block
    const int nb      = (N + 255) / 256;

    // layer 0: x[:,4:10] -> A
    nnconv_node<6, 32, false, 10, 4><<<nb, 256, 0, stream>>>(x, p[0][4], p[0][5], A, N);
    nnconv_edge_mfma<8, 6, 32, false, 10, 4><<<eblocks, 256, 0, stream>>>(
        x, src, dst, ea, p[0][0], p[0][1], bswz0, A, E);

    // layer 1: relu(A) -> B
    nnconv_node<32, 32, true, 32, 0><<<nb, 256, 0, stream>>>(A, p[1][4], p[1][5], Bbuf, N);
    nnconv_edge_mfma<32, 32, 32, true, 32, 0><<<eblocks, 256, 0, stream>>>(
        A, src, dst, ea, p[1][0], p[1][1], bswz1, Bbuf, E);

    // layer 2: relu(B) -> A
    nnconv_node<32, 32, true, 32, 0><<<nb, 256, 0, stream>>>(Bbuf, p[2][4], p[2][5], A, N);
    nnconv_edge_mfma<32, 32, 32, true, 32, 0><<<eblocks, 256, 0, stream>>>(
        Bbuf, src, dst, ea, p[2][0], p[2][1], bswz2, A, E);

    // layer 3: relu(A) -> out (N x 2)
    nnconv_node<32, 2, true, 32, 0><<<nb, 256, 0, stream>>>(A, p[3][4], p[3][5], out, N);
    nnconv_edge_mfma<32, 32, 2, true, 32, 0><<<eblocks, 256, 0, stream>>>(
        A, src, dst, ea, p[3][0], p[3][1], bswz3, out, E);
}